// Round 1
// baseline (255.937 us; speedup 1.0000x reference)
//
#include <hip/hip_runtime.h>
#include <math.h>

typedef _Float16 half8 __attribute__((ext_vector_type(8)));
typedef _Float16 half4 __attribute__((ext_vector_type(4)));
typedef float f32x4 __attribute__((ext_vector_type(4)));

#define HDIM 128
#define WHALFS 65536                      // packed W1|W2|W3 total halfs (128 KB)
#define SCR_HALFS 2048                    // per-wave scratch: 16 rows x 128 halfs (4 KB), XOR-swizzled
#define LDS_HALFS (WHALFS + 8 * SCR_HALFS)  // 81920 halfs
#define LDS_BYTES (LDS_HALFS * 2)           // 163840 B == 160 KiB exactly (AITER precedent: full LDS usable)

// ---------------------------------------------------------------------------
// Prep: x (N x 128 fp32) -> fp16; pack W1/W2/W3 into MFMA *A-operand* frag
// order for the transposed GEMM (A = W^T):
//   frag(ct,ks), lane: A[m=ct*16+(lane&15)][k=ks*32+(lane>>4)*8+j] = W[k][m]
// ---------------------------------------------------------------------------
__global__ __launch_bounds__(256) void prep_kernel(
    const float* __restrict__ x,  const float* __restrict__ W1,
    const float* __restrict__ W2, const float* __restrict__ W3,
    _Float16* __restrict__ xh,  _Float16* __restrict__ W1p,
    _Float16* __restrict__ W2p, _Float16* __restrict__ W3p, int NF)
{
    int bid = blockIdx.x;
    if (bid < 32) {
        int t = bid * 256 + threadIdx.x;   // 0..8191
        const float* W; _Float16* Wp; int KS; int u;
        if (t < 4096)      { W = W1; Wp = W1p; KS = 8; u = t; }          // 256x128
        else if (t < 6144) { W = W2; Wp = W2p; KS = 4; u = t - 4096; }   // 128x128
        else               { W = W3; Wp = W3p; KS = 4; u = t - 6144; }   // 128x128
        int lane = u & 63;
        int fk   = u >> 6;            // ct*KS + ks
        int ks   = fk % KS;
        int ct   = fk / KS;
        int m    = ct * 16 + (lane & 15);
        int k0   = ks * 32 + (lane >> 4) * 8;
        half8 v;
        #pragma unroll
        for (int j = 0; j < 8; ++j) v[j] = (_Float16)W[(k0 + j) * HDIM + m];
        *(half8*)(Wp + (size_t)u * 8) = v;
    } else {
        long i = (long)(bid - 32) * 2048 + (long)threadIdx.x * 8;
        if (i + 8 <= (long)NF) {
            const float4* xf = (const float4*)(x + i);
            float4 f0 = xf[0], f1 = xf[1];
            half8 v;
            v[0] = (_Float16)f0.x; v[1] = (_Float16)f0.y;
            v[2] = (_Float16)f0.z; v[3] = (_Float16)f0.w;
            v[4] = (_Float16)f1.x; v[5] = (_Float16)f1.y;
            v[6] = (_Float16)f1.z; v[7] = (_Float16)f1.w;
            *(half8*)(xh + i) = v;
        }
    }
}

// ---------------------------------------------------------------------------
// Epilogue: relu(acc + bias) -> fp16 scratch [edge(l15)][hidden], then pull
// next layer's B-frags (B[k=hidden][n=edge]) back as b128.
// Scratch row stride is 128 halfs (256 B) with an XOR swizzle on the
// within-row half-index: idx ^= (l15&7)<<3.  This keeps the b64 writes at
// ~2-way bank aliasing (free) and the b128 reads equivalent to contiguous,
// while shrinking scratch to 4 KB/wave so 8 waves fit next to 128 KB of
// weights in exactly 160 KiB of LDS.
// ---------------------------------------------------------------------------
__device__ __forceinline__ void epi_extract(
    f32x4 (&acc)[4][8], const float* __restrict__ bias,
    _Float16* __restrict__ scr, int l15, int quad, int sw, half8 (&bh)[4][4])
{
    float4 bv[8];
    #pragma unroll
    for (int ct = 0; ct < 8; ++ct)
        bv[ct] = *(const float4*)(bias + ct * 16 + quad * 4);
    #pragma unroll
    for (int nt = 0; nt < 4; ++nt) {
        #pragma unroll
        for (int ct = 0; ct < 8; ++ct) {
            half4 h;
            h[0] = (_Float16)fmaxf(acc[nt][ct][0] + bv[ct].x, 0.f);
            h[1] = (_Float16)fmaxf(acc[nt][ct][1] + bv[ct].y, 0.f);
            h[2] = (_Float16)fmaxf(acc[nt][ct][2] + bv[ct].z, 0.f);
            h[3] = (_Float16)fmaxf(acc[nt][ct][3] + bv[ct].w, 0.f);
            *(half4*)(scr + ((l15 * 128 + ct * 16 + quad * 4) ^ sw)) = h; // ds_write_b64
            acc[nt][ct] = f32x4{0.f, 0.f, 0.f, 0.f};
        }
        #pragma unroll
        for (int ks = 0; ks < 4; ++ks)                                    // ds_read_b128
            bh[nt][ks] = *(const half8*)(scr + ((l15 * 128 + ks * 32 + quad * 8) ^ sw));
    }
}

__device__ __forceinline__ void layer_mfma(
    f32x4 (&acc)[4][8], const _Float16* __restrict__ Wl,
    half8 (&bh)[4][4], int lane)
{
    #pragma unroll
    for (int ks = 0; ks < 4; ++ks) {
        half8 aw[8];
        #pragma unroll
        for (int ct = 0; ct < 8; ++ct)
            aw[ct] = *(const half8*)(Wl + ((size_t)((ct * 4 + ks) * 64 + lane)) * 8);
        #pragma unroll
        for (int nt = 0; nt < 4; ++nt)
            #pragma unroll
            for (int ct = 0; ct < 8; ++ct)
                acc[nt][ct] = __builtin_amdgcn_mfma_f32_16x16x32_f16(
                    aw[ct], bh[nt][ks], acc[nt][ct], 0, 0, 0);
    }
}

// ---------------------------------------------------------------------------
// Persistent fused MLP, transposed GEMM: D[hidden][edge] = W^T (A) x ef^T (B).
// grid = 256 blocks x 512 thr (8 waves); 160 KiB LDS -> 1 block/CU, but now
// 8 waves/CU = 2 waves/SIMD (was 1).  Each wave owns 64 edges (4 n-tiles of
// 16) per tile iteration; tile = 512 edges/block.  All weights live in LDS.
// ---------------------------------------------------------------------------
__global__ __launch_bounds__(512, 2) void edge_mlp_kernel(
    const int* __restrict__ ei, const _Float16* __restrict__ xh,
    const _Float16* __restrict__ wpack,   // W1p|W2p|W3p contiguous, 65536 halfs
    const float* __restrict__ b1, const float* __restrict__ b2,
    const float* __restrict__ b3, const float* __restrict__ W4,
    const float* __restrict__ b4, float* __restrict__ out, int E)
{
    extern __shared__ _Float16 lds[];

    // stage 128 KB of packed weights, once per (persistent) block
    {
        float4* dst = (float4*)lds;
        const float4* src = (const float4*)wpack;
        #pragma unroll
        for (int i = 0; i < 16; ++i)
            dst[i * 512 + threadIdx.x] = src[i * 512 + threadIdx.x];
    }
    __syncthreads();

    const int tid  = threadIdx.x;
    const int wave = tid >> 6;
    const int lane = tid & 63;
    const int l15  = lane & 15;
    const int quad = lane >> 4;
    const int sw   = (l15 & 7) << 3;      // scratch XOR swizzle (halfs)

    const _Float16* W1l = lds;
    const _Float16* W2l = lds + 32768;
    const _Float16* W3l = lds + 49152;
    _Float16* scr = lds + WHALFS + wave * SCR_HALFS;

    const int ntiles = (E + 511) >> 9;
    const float b4v = b4[0];

    for (int t = blockIdx.x; t < ntiles; t += gridDim.x) {
        const int base = t * 512 + wave * 64;

        // ---- gather layer-1 B-frags: B[k=concat-feat][n=edge] ----
        half8 bef[4][8];
        #pragma unroll
        for (int nt = 0; nt < 4; ++nt) {
            const int row = min(base + nt * 16 + l15, E - 1);
            const _Float16* pi = xh + (size_t)ei[row] * HDIM;
            const _Float16* pj = xh + (size_t)ei[E + row] * HDIM;
            #pragma unroll
            for (int ks = 0; ks < 4; ++ks) {
                bef[nt][ks]     = *(const half8*)(pi + ks * 32 + quad * 8);
                bef[nt][4 + ks] = *(const half8*)(pj + ks * 32 + quad * 8);
            }
        }

        f32x4 acc[4][8];
        #pragma unroll
        for (int nt = 0; nt < 4; ++nt)
            #pragma unroll
            for (int ct = 0; ct < 8; ++ct) acc[nt][ct] = f32x4{0.f, 0.f, 0.f, 0.f};

        // ---- layer 1: K=256 ----
        #pragma unroll
        for (int ks = 0; ks < 8; ++ks) {
            half8 aw[8];
            #pragma unroll
            for (int ct = 0; ct < 8; ++ct)
                aw[ct] = *(const half8*)(W1l + ((size_t)((ct * 8 + ks) * 64 + lane)) * 8);
            #pragma unroll
            for (int nt = 0; nt < 4; ++nt)
                #pragma unroll
                for (int ct = 0; ct < 8; ++ct)
                    acc[nt][ct] = __builtin_amdgcn_mfma_f32_16x16x32_f16(
                        aw[ct], bef[nt][ks], acc[nt][ct], 0, 0, 0);
        }

        half8 bh[4][4];
        epi_extract(acc, b1, scr, l15, quad, sw, bh);  // h1 -> B-frags
        layer_mfma(acc, W2l, bh, lane);                // layer 2
        epi_extract(acc, b2, scr, l15, quad, sw, bh);  // h2 -> B-frags
        layer_mfma(acc, W3l, bh, lane);                // layer 3

        // ---- layer 4: per-edge dot over hidden + sigmoid ----
        #pragma unroll
        for (int nt = 0; nt < 4; ++nt) {
            float s = 0.f;
            #pragma unroll
            for (int ct = 0; ct < 8; ++ct) {
                float4 b3v = *(const float4*)(b3 + ct * 16 + quad * 4);
                float4 w4v = *(const float4*)(W4 + ct * 16 + quad * 4);
                s += fmaxf(acc[nt][ct][0] + b3v.x, 0.f) * w4v.x;
                s += fmaxf(acc[nt][ct][1] + b3v.y, 0.f) * w4v.y;
                s += fmaxf(acc[nt][ct][2] + b3v.z, 0.f) * w4v.z;
                s += fmaxf(acc[nt][ct][3] + b3v.w, 0.f) * w4v.w;
            }
            s += __shfl_xor(s, 16, 64);   // sum across quads (same l15)
            s += __shfl_xor(s, 32, 64);
            const int row = base + nt * 16 + l15;
            if (quad == 0 && row < E)
                out[row] = 1.f / (1.f + __expf(-(s + b4v)));
        }
    }
}

// ---------------------------------------------------------------------------
extern "C" void kernel_launch(void* const* d_in, const int* in_sizes, int n_in,
                              void* d_out, int out_size, void* d_ws, size_t ws_size,
                              hipStream_t stream)
{
    const float* x  = (const float*)d_in[0];
    const int*   ei = (const int*)d_in[1];
    const float* W1 = (const float*)d_in[2];
    const float* b1 = (const float*)d_in[3];
    const float* W2 = (const float*)d_in[4];
    const float* b2 = (const float*)d_in[5];
    const float* W3 = (const float*)d_in[6];
    const float* b3 = (const float*)d_in[7];
    const float* W4 = (const float*)d_in[8];
    const float* b4 = (const float*)d_in[9];
    float* out = (float*)d_out;

    const int NF = in_sizes[0];    // N*F = 12,800,000
    const int E  = out_size;       // 625,000

    // ws layout (halfs): [ xh : NF ][ W1p : 32768 ][ W2p : 16384 ][ W3p : 16384 ]
    _Float16* xh  = (_Float16*)d_ws;
    _Float16* W1p = xh + NF;
    _Float16* W2p = W1p + 32768;
    _Float16* W3p = W2p + 16384;

    const int xblocks = (NF + 2047) / 2048;
    prep_kernel<<<32 + xblocks, 256, 0, stream>>>(x, W1, W2, W3, xh, W1p, W2p, W3p, NF);

    hipFuncSetAttribute((const void*)edge_mlp_kernel,
                        hipFuncAttributeMaxDynamicSharedMemorySize, LDS_BYTES);
    edge_mlp_kernel<<<256, 512, LDS_BYTES, stream>>>(ei, xh, W1p,
                                                     b1, b2, b3, W4, b4, out, E);
}

// Round 2
// 248.758 us; speedup vs baseline: 1.0289x; 1.0289x over previous
//
#include <hip/hip_runtime.h>
#include <math.h>

typedef _Float16 half8 __attribute__((ext_vector_type(8)));
typedef _Float16 half4 __attribute__((ext_vector_type(4)));
typedef float f32x4 __attribute__((ext_vector_type(4)));

#define HDIM 128
#define WHALFS 65536                      // packed W1|W2|W3 total halfs (128 KB)
#define SCR_HALFS 2048                    // per-wave scratch: 16 rows x 128 halfs (4 KB), XOR-swizzled
#define LDS_HALFS (WHALFS + 8 * SCR_HALFS)  // 81920 halfs
#define LDS_BYTES (LDS_HALFS * 2)           // 163840 B == 160 KiB exactly

// ---------------------------------------------------------------------------
// Prep: x (N x 128 fp32) -> fp16; pack W1/W2/W3 into MFMA *A-operand* frag
// order for the transposed GEMM (A = W^T):
//   frag(ct,ks), lane: A[m=ct*16+(lane&15)][k=ks*32+(lane>>4)*8+j] = W[k][m]
// ---------------------------------------------------------------------------
__global__ __launch_bounds__(256) void prep_kernel(
    const float* __restrict__ x,  const float* __restrict__ W1,
    const float* __restrict__ W2, const float* __restrict__ W3,
    _Float16* __restrict__ xh,  _Float16* __restrict__ W1p,
    _Float16* __restrict__ W2p, _Float16* __restrict__ W3p, int NF)
{
    int bid = blockIdx.x;
    if (bid < 32) {
        int t = bid * 256 + threadIdx.x;   // 0..8191
        const float* W; _Float16* Wp; int KS; int u;
        if (t < 4096)      { W = W1; Wp = W1p; KS = 8; u = t; }          // 256x128
        else if (t < 6144) { W = W2; Wp = W2p; KS = 4; u = t - 4096; }   // 128x128
        else               { W = W3; Wp = W3p; KS = 4; u = t - 6144; }   // 128x128
        int lane = u & 63;
        int fk   = u >> 6;            // ct*KS + ks
        int ks   = fk % KS;
        int ct   = fk / KS;
        int m    = ct * 16 + (lane & 15);
        int k0   = ks * 32 + (lane >> 4) * 8;
        half8 v;
        #pragma unroll
        for (int j = 0; j < 8; ++j) v[j] = (_Float16)W[(k0 + j) * HDIM + m];
        *(half8*)(Wp + (size_t)u * 8) = v;
    } else {
        long i = (long)(bid - 32) * 2048 + (long)threadIdx.x * 8;
        if (i + 8 <= (long)NF) {
            const float4* xf = (const float4*)(x + i);
            float4 f0 = xf[0], f1 = xf[1];
            half8 v;
            v[0] = (_Float16)f0.x; v[1] = (_Float16)f0.y;
            v[2] = (_Float16)f0.z; v[3] = (_Float16)f0.w;
            v[4] = (_Float16)f1.x; v[5] = (_Float16)f1.y;
            v[6] = (_Float16)f1.z; v[7] = (_Float16)f1.w;
            *(half8*)(xh + i) = v;
        }
    }
}

// ---------------------------------------------------------------------------
// Epilogue: relu(acc + bias) -> fp16 scratch [edge(l15)][hidden], then pull
// next layer's B-frags (B[k=hidden][n=edge]) back as b128.
// Scratch row stride 128 halfs (256 B), XOR swizzle idx ^= (l15&7)<<3:
// b64 writes land at 2-way bank aliasing (free), b128 reads equivalent to
// contiguous; 4 KB/wave so 8 waves fit next to 128 KB of weights in 160 KiB.
// ---------------------------------------------------------------------------
__device__ __forceinline__ void epi_extract(
    f32x4 (&acc)[4][8], const float* __restrict__ bias,
    _Float16* __restrict__ scr, int l15, int quad, int sw, half8 (&bh)[4][4])
{
    float4 bv[8];
    #pragma unroll
    for (int ct = 0; ct < 8; ++ct)
        bv[ct] = *(const float4*)(bias + ct * 16 + quad * 4);
    #pragma unroll
    for (int nt = 0; nt < 4; ++nt) {
        #pragma unroll
        for (int ct = 0; ct < 8; ++ct) {
            half4 h;
            h[0] = (_Float16)fmaxf(acc[nt][ct][0] + bv[ct].x, 0.f);
            h[1] = (_Float16)fmaxf(acc[nt][ct][1] + bv[ct].y, 0.f);
            h[2] = (_Float16)fmaxf(acc[nt][ct][2] + bv[ct].z, 0.f);
            h[3] = (_Float16)fmaxf(acc[nt][ct][3] + bv[ct].w, 0.f);
            *(half4*)(scr + ((l15 * 128 + ct * 16 + quad * 4) ^ sw)) = h; // ds_write_b64
            acc[nt][ct] = f32x4{0.f, 0.f, 0.f, 0.f};
        }
        #pragma unroll
        for (int ks = 0; ks < 4; ++ks)                                    // ds_read_b128
            bh[nt][ks] = *(const half8*)(scr + ((l15 * 128 + ks * 32 + quad * 8) ^ sw));
    }
}

__device__ __forceinline__ void layer_mfma(
    f32x4 (&acc)[4][8], const _Float16* __restrict__ Wl,
    half8 (&bh)[4][4], int lane)
{
    #pragma unroll
    for (int ks = 0; ks < 4; ++ks) {
        half8 aw[8];
        #pragma unroll
        for (int ct = 0; ct < 8; ++ct)
            aw[ct] = *(const half8*)(Wl + ((size_t)((ct * 4 + ks) * 64 + lane)) * 8);
        #pragma unroll
        for (int nt = 0; nt < 4; ++nt)
            #pragma unroll
            for (int ct = 0; ct < 8; ++ct)
                acc[nt][ct] = __builtin_amdgcn_mfma_f32_16x16x32_f16(
                    aw[ct], bh[nt][ks], acc[nt][ct], 0, 0, 0);
    }
}

// ---------------------------------------------------------------------------
// Persistent fused MLP, transposed GEMM: D[hidden][edge] = W^T (A) x ef^T (B).
// grid = 256 blocks x 512 thr (8 waves, 2 waves/SIMD); 160 KiB LDS ->
// 1 block/CU.  Total register budget at 2 waves/SIMD is 256 = 128 acc
// (AGPR) + 128 arch, so layer-1's gathered B-frags are held HALF at a
// time (x_i half: K=0..127, then x_j half: K=128..255) -- 64 regs instead
// of round-1's 128, which spilled.  Each wave owns 64 edges/tile.
// ---------------------------------------------------------------------------
__global__ __launch_bounds__(512, 2) void edge_mlp_kernel(
    const int* __restrict__ ei, const _Float16* __restrict__ xh,
    const _Float16* __restrict__ wpack,   // W1p|W2p|W3p contiguous, 65536 halfs
    const float* __restrict__ b1, const float* __restrict__ b2,
    const float* __restrict__ b3, const float* __restrict__ W4,
    const float* __restrict__ b4, float* __restrict__ out, int E)
{
    extern __shared__ _Float16 lds[];

    // stage 128 KB of packed weights, once per (persistent) block
    {
        float4* dst = (float4*)lds;
        const float4* src = (const float4*)wpack;
        #pragma unroll
        for (int i = 0; i < 16; ++i)
            dst[i * 512 + threadIdx.x] = src[i * 512 + threadIdx.x];
    }
    __syncthreads();

    const int tid  = threadIdx.x;
    const int wave = tid >> 6;
    const int lane = tid & 63;
    const int l15  = lane & 15;
    const int quad = lane >> 4;
    const int sw   = (l15 & 7) << 3;      // scratch XOR swizzle (halfs)

    const _Float16* W1l = lds;
    const _Float16* W2l = lds + 32768;
    const _Float16* W3l = lds + 49152;
    _Float16* scr = lds + WHALFS + wave * SCR_HALFS;

    const int ntiles = (E + 511) >> 9;
    const float b4v = b4[0];

    for (int t = blockIdx.x; t < ntiles; t += gridDim.x) {
        const int base = t * 512 + wave * 64;

        // edge indices for all 4 n-tiles (issued early; ~12 arch regs)
        int rows[4], gi[4], gj[4];
        #pragma unroll
        for (int nt = 0; nt < 4; ++nt) {
            rows[nt] = min(base + nt * 16 + l15, E - 1);
            gi[nt] = ei[rows[nt]];
            gj[nt] = ei[E + rows[nt]];
        }

        f32x4 acc[4][8];
        #pragma unroll
        for (int nt = 0; nt < 4; ++nt)
            #pragma unroll
            for (int ct = 0; ct < 8; ++ct) acc[nt][ct] = f32x4{0.f, 0.f, 0.f, 0.f};

        half8 bef[4][4];

        // ---- layer 1, half 1: K = 0..127 (x_i features) ----
        #pragma unroll
        for (int nt = 0; nt < 4; ++nt) {
            const _Float16* pi = xh + (size_t)gi[nt] * HDIM;
            #pragma unroll
            for (int ks = 0; ks < 4; ++ks)
                bef[nt][ks] = *(const half8*)(pi + ks * 32 + quad * 8);
        }
        #pragma unroll
        for (int ks = 0; ks < 4; ++ks) {
            half8 aw[8];
            #pragma unroll
            for (int ct = 0; ct < 8; ++ct)
                aw[ct] = *(const half8*)(W1l + ((size_t)((ct * 8 + ks) * 64 + lane)) * 8);
            #pragma unroll
            for (int nt = 0; nt < 4; ++nt)
                #pragma unroll
                for (int ct = 0; ct < 8; ++ct)
                    acc[nt][ct] = __builtin_amdgcn_mfma_f32_16x16x32_f16(
                        aw[ct], bef[nt][ks], acc[nt][ct], 0, 0, 0);
        }

        // ---- layer 1, half 2: K = 128..255 (x_j features) ----
        #pragma unroll
        for (int nt = 0; nt < 4; ++nt) {
            const _Float16* pj = xh + (size_t)gj[nt] * HDIM;
            #pragma unroll
            for (int ks = 0; ks < 4; ++ks)
                bef[nt][ks] = *(const half8*)(pj + ks * 32 + quad * 8);
        }
        #pragma unroll
        for (int ks = 0; ks < 4; ++ks) {
            half8 aw[8];
            #pragma unroll
            for (int ct = 0; ct < 8; ++ct)
                aw[ct] = *(const half8*)(W1l + ((size_t)((ct * 8 + 4 + ks) * 64 + lane)) * 8);
            #pragma unroll
            for (int nt = 0; nt < 4; ++nt)
                #pragma unroll
                for (int ct = 0; ct < 8; ++ct)
                    acc[nt][ct] = __builtin_amdgcn_mfma_f32_16x16x32_f16(
                        aw[ct], bef[nt][ks], acc[nt][ct], 0, 0, 0);
        }

        half8 bh[4][4];
        epi_extract(acc, b1, scr, l15, quad, sw, bh);  // h1 -> B-frags
        layer_mfma(acc, W2l, bh, lane);                // layer 2
        epi_extract(acc, b2, scr, l15, quad, sw, bh);  // h2 -> B-frags
        layer_mfma(acc, W3l, bh, lane);                // layer 3

        // ---- layer 4: per-edge dot over hidden + sigmoid ----
        #pragma unroll
        for (int nt = 0; nt < 4; ++nt) {
            float s = 0.f;
            #pragma unroll
            for (int ct = 0; ct < 8; ++ct) {
                float4 b3v = *(const float4*)(b3 + ct * 16 + quad * 4);
                float4 w4v = *(const float4*)(W4 + ct * 16 + quad * 4);
                s += fmaxf(acc[nt][ct][0] + b3v.x, 0.f) * w4v.x;
                s += fmaxf(acc[nt][ct][1] + b3v.y, 0.f) * w4v.y;
                s += fmaxf(acc[nt][ct][2] + b3v.z, 0.f) * w4v.z;
                s += fmaxf(acc[nt][ct][3] + b3v.w, 0.f) * w4v.w;
            }
            s += __shfl_xor(s, 16, 64);   // sum across quads (same l15)
            s += __shfl_xor(s, 32, 64);
            const int row = base + nt * 16 + l15;
            if (quad == 0 && row < E)
                out[row] = 1.f / (1.f + __expf(-(s + b4v)));
        }
    }
}

// ---------------------------------------------------------------------------
extern "C" void kernel_launch(void* const* d_in, const int* in_sizes, int n_in,
                              void* d_out, int out_size, void* d_ws, size_t ws_size,
                              hipStream_t stream)
{
    const float* x  = (const float*)d_in[0];
    const int*   ei = (const int*)d_in[1];
    const float* W1 = (const float*)d_in[2];
    const float* b1 = (const float*)d_in[3];
    const float* W2 = (const float*)d_in[4];
    const float* b2 = (const float*)d_in[5];
    const float* W3 = (const float*)d_in[6];
    const float* b3 = (const float*)d_in[7];
    const float* W4 = (const float*)d_in[8];
    const float* b4 = (const float*)d_in[9];
    float* out = (float*)d_out;

    const int NF = in_sizes[0];    // N*F = 12,800,000
    const int E  = out_size;       // 625,000

    // ws layout (halfs): [ xh : NF ][ W1p : 32768 ][ W2p : 16384 ][ W3p : 16384 ]
    _Float16* xh  = (_Float16*)d_ws;
    _Float16* W1p = xh + NF;
    _Float16* W2p = W1p + 32768;
    _Float16* W3p = W2p + 16384;

    const int xblocks = (NF + 2047) / 2048;
    prep_kernel<<<32 + xblocks, 256, 0, stream>>>(x, W1, W2, W3, xh, W1p, W2p, W3p, NF);

    hipFuncSetAttribute((const void*)edge_mlp_kernel,
                        hipFuncAttributeMaxDynamicSharedMemorySize, LDS_BYTES);
    edge_mlp_kernel<<<256, 512, LDS_BYTES, stream>>>(ei, xh, W1p,
                                                     b1, b2, b3, W4, b4, out, E);
}

// Round 3
// 233.624 us; speedup vs baseline: 1.0955x; 1.0648x over previous
//
#include <hip/hip_runtime.h>
#include <math.h>

typedef _Float16 half8 __attribute__((ext_vector_type(8)));
typedef _Float16 half4 __attribute__((ext_vector_type(4)));
typedef float f32x4 __attribute__((ext_vector_type(4)));

#define HDIM 128
#define WHALFS 65536                      // packed W1|W2|W3 total halfs (128 KB)
#define SCR_HALFS 2048                    // per-wave scratch: 16 rows x 128 halfs (4 KB), XOR-swizzled
#define LDS_HALFS (WHALFS + 8 * SCR_HALFS)  // 81920 halfs
#define LDS_BYTES (LDS_HALFS * 2)           // 163840 B == 160 KiB exactly

// ---------------------------------------------------------------------------
// Prep: x (N x 128 fp32) -> fp16; pack W1/W2/W3 into MFMA *A-operand* frag
// order for the transposed GEMM (A = W^T):
//   frag(ct,ks), lane: A[m=ct*16+(lane&15)][k=ks*32+(lane>>4)*8+j] = W[k][m]
// ---------------------------------------------------------------------------
__global__ __launch_bounds__(256) void prep_kernel(
    const float* __restrict__ x,  const float* __restrict__ W1,
    const float* __restrict__ W2, const float* __restrict__ W3,
    _Float16* __restrict__ xh,  _Float16* __restrict__ W1p,
    _Float16* __restrict__ W2p, _Float16* __restrict__ W3p, int NF)
{
    int bid = blockIdx.x;
    if (bid < 32) {
        int t = bid * 256 + threadIdx.x;   // 0..8191
        const float* W; _Float16* Wp; int KS; int u;
        if (t < 4096)      { W = W1; Wp = W1p; KS = 8; u = t; }          // 256x128
        else if (t < 6144) { W = W2; Wp = W2p; KS = 4; u = t - 4096; }   // 128x128
        else               { W = W3; Wp = W3p; KS = 4; u = t - 6144; }   // 128x128
        int lane = u & 63;
        int fk   = u >> 6;            // ct*KS + ks
        int ks   = fk % KS;
        int ct   = fk / KS;
        int m    = ct * 16 + (lane & 15);
        int k0   = ks * 32 + (lane >> 4) * 8;
        half8 v;
        #pragma unroll
        for (int j = 0; j < 8; ++j) v[j] = (_Float16)W[(k0 + j) * HDIM + m];
        *(half8*)(Wp + (size_t)u * 8) = v;
    } else {
        long i = (long)(bid - 32) * 2048 + (long)threadIdx.x * 8;
        if (i + 8 <= (long)NF) {
            const float4* xf = (const float4*)(x + i);
            float4 f0 = xf[0], f1 = xf[1];
            half8 v;
            v[0] = (_Float16)f0.x; v[1] = (_Float16)f0.y;
            v[2] = (_Float16)f0.z; v[3] = (_Float16)f0.w;
            v[4] = (_Float16)f1.x; v[5] = (_Float16)f1.y;
            v[6] = (_Float16)f1.z; v[7] = (_Float16)f1.w;
            *(half8*)(xh + i) = v;
        }
    }
}

// ---------------------------------------------------------------------------
// Epilogue: relu(acc + bias) -> fp16 scratch [edge(l15)][hidden], then pull
// next layer's B-frags (B[k=hidden][n=edge]) back as b128.
// Scratch row stride 128 halfs (256 B), XOR swizzle idx ^= (l15&7)<<3:
// b64 writes land at 2-way bank aliasing (free), b128 reads equivalent to
// contiguous; 4 KB/wave so 8 waves fit next to 128 KB of weights in 160 KiB.
// nt=2: scratch tile (16 edges) reused serially across the two n-tiles.
// ---------------------------------------------------------------------------
__device__ __forceinline__ void epi_extract(
    f32x4 (&acc)[2][8], const float* __restrict__ bias,
    _Float16* __restrict__ scr, int l15, int quad, int sw, half8 (&bh)[2][4])
{
    float4 bv[8];
    #pragma unroll
    for (int ct = 0; ct < 8; ++ct)
        bv[ct] = *(const float4*)(bias + ct * 16 + quad * 4);
    #pragma unroll
    for (int nt = 0; nt < 2; ++nt) {
        #pragma unroll
        for (int ct = 0; ct < 8; ++ct) {
            half4 h;
            h[0] = (_Float16)fmaxf(acc[nt][ct][0] + bv[ct].x, 0.f);
            h[1] = (_Float16)fmaxf(acc[nt][ct][1] + bv[ct].y, 0.f);
            h[2] = (_Float16)fmaxf(acc[nt][ct][2] + bv[ct].z, 0.f);
            h[3] = (_Float16)fmaxf(acc[nt][ct][3] + bv[ct].w, 0.f);
            *(half4*)(scr + ((l15 * 128 + ct * 16 + quad * 4) ^ sw)) = h; // ds_write_b64
            acc[nt][ct] = f32x4{0.f, 0.f, 0.f, 0.f};
        }
        #pragma unroll
        for (int ks = 0; ks < 4; ++ks)                                    // ds_read_b128
            bh[nt][ks] = *(const half8*)(scr + ((l15 * 128 + ks * 32 + quad * 8) ^ sw));
    }
}

__device__ __forceinline__ void layer_mfma(
    f32x4 (&acc)[2][8], const _Float16* __restrict__ Wl,
    half8 (&bh)[2][4], int lane)
{
    #pragma unroll
    for (int ks = 0; ks < 4; ++ks) {
        half8 aw[8];
        #pragma unroll
        for (int ct = 0; ct < 8; ++ct)
            aw[ct] = *(const half8*)(Wl + ((size_t)((ct * 4 + ks) * 64 + lane)) * 8);
        #pragma unroll
        for (int nt = 0; nt < 2; ++nt)
            #pragma unroll
            for (int ct = 0; ct < 8; ++ct)
                acc[nt][ct] = __builtin_amdgcn_mfma_f32_16x16x32_f16(
                    aw[ct], bh[nt][ks], acc[nt][ct], 0, 0, 0);
    }
}

// ---------------------------------------------------------------------------
// Persistent fused MLP, transposed GEMM: D[hidden][edge] = W^T (A) x ef^T (B).
// grid = 256 blocks x 512 thr (8 waves, 2 waves/SIMD); 160 KiB LDS ->
// 1 block/CU.  Register budget at 2 waves/SIMD is 256 total.  nt=2
// (32 edges/wave) keeps acc[2][8] at 64 AGPRs -> 192 arch regs for
// bef[2][8] (64) + aw (32) + addressing, so NOTHING spills (rounds 1-2
// spilled ~89 MB/dispatch with nt=4's 128-AGPR acc leaving only 128 arch).
// Cost: weight LDS reads amortize over 2 n-tiles instead of 4 (~33 us
// chip-wide LDS floor) -- still far under the MFMA+latency budget.
// ---------------------------------------------------------------------------
__global__ __launch_bounds__(512, 2) void edge_mlp_kernel(
    const int* __restrict__ ei, const _Float16* __restrict__ xh,
    const _Float16* __restrict__ wpack,   // W1p|W2p|W3p contiguous, 65536 halfs
    const float* __restrict__ b1, const float* __restrict__ b2,
    const float* __restrict__ b3, const float* __restrict__ W4,
    const float* __restrict__ b4, float* __restrict__ out, int E)
{
    extern __shared__ _Float16 lds[];

    // stage 128 KB of packed weights, once per (persistent) block
    {
        float4* dst = (float4*)lds;
        const float4* src = (const float4*)wpack;
        #pragma unroll
        for (int i = 0; i < 16; ++i)
            dst[i * 512 + threadIdx.x] = src[i * 512 + threadIdx.x];
    }
    __syncthreads();

    const int tid  = threadIdx.x;
    const int wave = tid >> 6;
    const int lane = tid & 63;
    const int l15  = lane & 15;
    const int quad = lane >> 4;
    const int sw   = (l15 & 7) << 3;      // scratch XOR swizzle (halfs)

    const _Float16* W1l = lds;
    const _Float16* W2l = lds + 32768;
    const _Float16* W3l = lds + 49152;
    _Float16* scr = lds + WHALFS + wave * SCR_HALFS;

    const int ntiles = (E + 255) >> 8;    // 256 edges per block tile
    const float b4v = b4[0];

    for (int t = blockIdx.x; t < ntiles; t += gridDim.x) {
        const int base = t * 256 + wave * 32;

        // ---- gather layer-1 B-frags for both n-tiles: 16 loads in flight ----
        half8 bef[2][8];
        #pragma unroll
        for (int nt = 0; nt < 2; ++nt) {
            const int row = min(base + nt * 16 + l15, E - 1);
            const _Float16* pi = xh + (size_t)ei[row] * HDIM;
            const _Float16* pj = xh + (size_t)ei[E + row] * HDIM;
            #pragma unroll
            for (int ks = 0; ks < 4; ++ks) {
                bef[nt][ks]     = *(const half8*)(pi + ks * 32 + quad * 8);
                bef[nt][4 + ks] = *(const half8*)(pj + ks * 32 + quad * 8);
            }
        }

        f32x4 acc[2][8];
        #pragma unroll
        for (int nt = 0; nt < 2; ++nt)
            #pragma unroll
            for (int ct = 0; ct < 8; ++ct) acc[nt][ct] = f32x4{0.f, 0.f, 0.f, 0.f};

        // ---- layer 1: K=256 ----
        #pragma unroll
        for (int ks = 0; ks < 8; ++ks) {
            half8 aw[8];
            #pragma unroll
            for (int ct = 0; ct < 8; ++ct)
                aw[ct] = *(const half8*)(W1l + ((size_t)((ct * 8 + ks) * 64 + lane)) * 8);
            #pragma unroll
            for (int nt = 0; nt < 2; ++nt)
                #pragma unroll
                for (int ct = 0; ct < 8; ++ct)
                    acc[nt][ct] = __builtin_amdgcn_mfma_f32_16x16x32_f16(
                        aw[ct], bef[nt][ks], acc[nt][ct], 0, 0, 0);
        }

        half8 bh[2][4];
        epi_extract(acc, b1, scr, l15, quad, sw, bh);  // h1 -> B-frags
        layer_mfma(acc, W2l, bh, lane);                // layer 2
        epi_extract(acc, b2, scr, l15, quad, sw, bh);  // h2 -> B-frags
        layer_mfma(acc, W3l, bh, lane);                // layer 3

        // ---- layer 4: per-edge dot over hidden + sigmoid ----
        #pragma unroll
        for (int nt = 0; nt < 2; ++nt) {
            float s = 0.f;
            #pragma unroll
            for (int ct = 0; ct < 8; ++ct) {
                float4 b3v = *(const float4*)(b3 + ct * 16 + quad * 4);
                float4 w4v = *(const float4*)(W4 + ct * 16 + quad * 4);
                s += fmaxf(acc[nt][ct][0] + b3v.x, 0.f) * w4v.x;
                s += fmaxf(acc[nt][ct][1] + b3v.y, 0.f) * w4v.y;
                s += fmaxf(acc[nt][ct][2] + b3v.z, 0.f) * w4v.z;
                s += fmaxf(acc[nt][ct][3] + b3v.w, 0.f) * w4v.w;
            }
            s += __shfl_xor(s, 16, 64);   // sum across quads (same l15)
            s += __shfl_xor(s, 32, 64);
            const int row = base + nt * 16 + l15;
            if (quad == 0 && row < E)
                out[row] = 1.f / (1.f + __expf(-(s + b4v)));
        }
    }
}

// ---------------------------------------------------------------------------
extern "C" void kernel_launch(void* const* d_in, const int* in_sizes, int n_in,
                              void* d_out, int out_size, void* d_ws, size_t ws_size,
                              hipStream_t stream)
{
    const float* x  = (const float*)d_in[0];
    const int*   ei = (const int*)d_in[1];
    const float* W1 = (const float*)d_in[2];
    const float* b1 = (const float*)d_in[3];
    const float* W2 = (const float*)d_in[4];
    const float* b2 = (const float*)d_in[5];
    const float* W3 = (const float*)d_in[6];
    const float* b3 = (const float*)d_in[7];
    const float* W4 = (const float*)d_in[8];
    const float* b4 = (const float*)d_in[9];
    float* out = (float*)d_out;

    const int NF = in_sizes[0];    // N*F = 12,800,000
    const int E  = out_size;       // 625,000

    // ws layout (halfs): [ xh : NF ][ W1p : 32768 ][ W2p : 16384 ][ W3p : 16384 ]
    _Float16* xh  = (_Float16*)d_ws;
    _Float16* W1p = xh + NF;
    _Float16* W2p = W1p + 32768;
    _Float16* W3p = W2p + 16384;

    const int xblocks = (NF + 2047) / 2048;
    prep_kernel<<<32 + xblocks, 256, 0, stream>>>(x, W1, W2, W3, xh, W1p, W2p, W3p, NF);

    hipFuncSetAttribute((const void*)edge_mlp_kernel,
                        hipFuncAttributeMaxDynamicSharedMemorySize, LDS_BYTES);
    edge_mlp_kernel<<<256, 512, LDS_BYTES, stream>>>(ei, xh, W1p,
                                                     b1, b2, b3, W4, b4, out, E);
}

// Round 4
// 211.925 us; speedup vs baseline: 1.2077x; 1.1024x over previous
//
#include <hip/hip_runtime.h>
#include <math.h>

typedef _Float16 half8 __attribute__((ext_vector_type(8)));
typedef _Float16 half4 __attribute__((ext_vector_type(4)));
typedef float f32x4 __attribute__((ext_vector_type(4)));

#define HDIM 128
#define WHALFS 65536                      // packed W1|W2|W3 total halfs (128 KB)
#define SCR_HALFS 2048                    // per-wave scratch: 16 rows x 128 halfs (4 KB), XOR-swizzled
#define LDS_HALFS (WHALFS + 8 * SCR_HALFS)  // 81920 halfs
#define LDS_BYTES (LDS_HALFS * 2)           // 163840 B == 160 KiB exactly

// ---------------------------------------------------------------------------
// Prep: x (N x 128 fp32) -> fp16; pack W1/W2/W3 into MFMA *A-operand* frag
// order for the transposed GEMM (A = W^T):
//   frag(ct,ks), lane: A[m=ct*16+(lane&15)][k=ks*32+(lane>>4)*8+j] = W[k][m]
// ---------------------------------------------------------------------------
__global__ __launch_bounds__(256) void prep_kernel(
    const float* __restrict__ x,  const float* __restrict__ W1,
    const float* __restrict__ W2, const float* __restrict__ W3,
    _Float16* __restrict__ xh,  _Float16* __restrict__ W1p,
    _Float16* __restrict__ W2p, _Float16* __restrict__ W3p, int NF)
{
    int bid = blockIdx.x;
    if (bid < 32) {
        int t = bid * 256 + threadIdx.x;   // 0..8191
        const float* W; _Float16* Wp; int KS; int u;
        if (t < 4096)      { W = W1; Wp = W1p; KS = 8; u = t; }          // 256x128
        else if (t < 6144) { W = W2; Wp = W2p; KS = 4; u = t - 4096; }   // 128x128
        else               { W = W3; Wp = W3p; KS = 4; u = t - 6144; }   // 128x128
        int lane = u & 63;
        int fk   = u >> 6;            // ct*KS + ks
        int ks   = fk % KS;
        int ct   = fk / KS;
        int m    = ct * 16 + (lane & 15);
        int k0   = ks * 32 + (lane >> 4) * 8;
        half8 v;
        #pragma unroll
        for (int j = 0; j < 8; ++j) v[j] = (_Float16)W[(k0 + j) * HDIM + m];
        *(half8*)(Wp + (size_t)u * 8) = v;
    } else {
        long i = (long)(bid - 32) * 2048 + (long)threadIdx.x * 8;
        if (i + 8 <= (long)NF) {
            const float4* xf = (const float4*)(x + i);
            float4 f0 = xf[0], f1 = xf[1];
            half8 v;
            v[0] = (_Float16)f0.x; v[1] = (_Float16)f0.y;
            v[2] = (_Float16)f0.z; v[3] = (_Float16)f0.w;
            v[4] = (_Float16)f1.x; v[5] = (_Float16)f1.y;
            v[6] = (_Float16)f1.z; v[7] = (_Float16)f1.w;
            *(half8*)(xh + i) = v;
        }
    }
}

// ---------------------------------------------------------------------------
// acc init = per-layer bias (exact: acc elem j <-> out-channel ct*16+quad*4+j,
// bias is constant over columns).  Removes bias regs/adds from the epilogue.
// ---------------------------------------------------------------------------
__device__ __forceinline__ void acc_bias_init(
    f32x4 (&acc)[2][8], const float* __restrict__ bias, int quad)
{
    #pragma unroll
    for (int ct = 0; ct < 8; ++ct) {
        float4 bv = *(const float4*)(bias + ct * 16 + quad * 4);
        f32x4 b = {bv.x, bv.y, bv.z, bv.w};
        acc[0][ct] = b;
        acc[1][ct] = b;
    }
}

// ---------------------------------------------------------------------------
// Epilogue: relu(acc) -> fp16 scratch [edge(l15)][hidden] (bias already in
// acc), pull next layer's B-frags back as b128, then re-init acc with the
// NEXT layer's bias.  Scratch row stride 128 halfs (256 B), XOR swizzle
// idx ^= (l15&7)<<3: b64 writes at 2-way bank aliasing (free), b128 reads
// equivalent to contiguous; 4 KB/wave.
// ---------------------------------------------------------------------------
__device__ __forceinline__ void epi_extract(
    f32x4 (&acc)[2][8], _Float16* __restrict__ scr, int l15, int quad, int sw,
    half8 (&bh)[2][4], const float* __restrict__ next_bias)
{
    #pragma unroll
    for (int nt = 0; nt < 2; ++nt) {
        #pragma unroll
        for (int ct = 0; ct < 8; ++ct) {
            half4 h;
            h[0] = (_Float16)fmaxf(acc[nt][ct][0], 0.f);
            h[1] = (_Float16)fmaxf(acc[nt][ct][1], 0.f);
            h[2] = (_Float16)fmaxf(acc[nt][ct][2], 0.f);
            h[3] = (_Float16)fmaxf(acc[nt][ct][3], 0.f);
            *(half4*)(scr + ((l15 * 128 + ct * 16 + quad * 4) ^ sw)) = h; // ds_write_b64
        }
        #pragma unroll
        for (int ks = 0; ks < 4; ++ks)                                    // ds_read_b128
            bh[nt][ks] = *(const half8*)(scr + ((l15 * 128 + ks * 32 + quad * 8) ^ sw));
    }
    acc_bias_init(acc, next_bias, quad);
}

__device__ __forceinline__ void layer_mfma(
    f32x4 (&acc)[2][8], const _Float16* __restrict__ Wl,
    half8 (&bh)[2][4], int lane)
{
    #pragma unroll
    for (int ks = 0; ks < 4; ++ks) {
        half8 aw[8];
        #pragma unroll
        for (int ct = 0; ct < 8; ++ct)
            aw[ct] = *(const half8*)(Wl + ((size_t)((ct * 4 + ks) * 64 + lane)) * 8);
        #pragma unroll
        for (int nt = 0; nt < 2; ++nt)
            #pragma unroll
            for (int ct = 0; ct < 8; ++ct)
                acc[nt][ct] = __builtin_amdgcn_mfma_f32_16x16x32_f16(
                    aw[ct], bh[nt][ks], acc[nt][ct], 0, 0, 0);
    }
}

// ---------------------------------------------------------------------------
// Persistent fused MLP, transposed GEMM: D[hidden][edge] = W^T (A) x ef^T (B).
// grid = 256 blocks x 512 thr (8 waves, 2 waves/SIMD); 160 KiB LDS ->
// 1 block/CU.  Unified RF budget at 2 waves/SIMD = 256/wave, which the
// compiler splits arch/accum (R1-R3 evidence: 128/128 split, arch pinned,
// ~25-90 MB spill traffic).  This version keeps the ARCH peak < 128:
//  - nt=2 -> acc[2][8] = 64 accum regs
//  - layer-1 strict half-split: bef[2][4] = 32 regs (x_i half then x_j half)
//  - biases folded into acc init -> epilogue live set is just bh + staging
// ---------------------------------------------------------------------------
__global__ __launch_bounds__(512, 2) void edge_mlp_kernel(
    const int* __restrict__ ei, const _Float16* __restrict__ xh,
    const _Float16* __restrict__ wpack,   // W1p|W2p|W3p contiguous, 65536 halfs
    const float* __restrict__ b1, const float* __restrict__ b2,
    const float* __restrict__ b3, const float* __restrict__ W4,
    const float* __restrict__ b4, float* __restrict__ out, int E)
{
    extern __shared__ _Float16 lds[];

    // stage 128 KB of packed weights, once per (persistent) block
    {
        float4* dst = (float4*)lds;
        const float4* src = (const float4*)wpack;
        #pragma unroll
        for (int i = 0; i < 16; ++i)
            dst[i * 512 + threadIdx.x] = src[i * 512 + threadIdx.x];
    }
    __syncthreads();

    const int tid  = threadIdx.x;
    const int wave = tid >> 6;
    const int lane = tid & 63;
    const int l15  = lane & 15;
    const int quad = lane >> 4;
    const int sw   = (l15 & 7) << 3;      // scratch XOR swizzle (halfs)

    const _Float16* W1l = lds;
    const _Float16* W2l = lds + 32768;
    const _Float16* W3l = lds + 49152;
    _Float16* scr = lds + WHALFS + wave * SCR_HALFS;

    const int ntiles = (E + 255) >> 8;    // 256 edges per block tile
    const float b4v = b4[0];

    for (int t = blockIdx.x; t < ntiles; t += gridDim.x) {
        const int base = t * 256 + wave * 32;

        // edge indices for both n-tiles
        int gi[2], gj[2];
        #pragma unroll
        for (int nt = 0; nt < 2; ++nt) {
            const int row = min(base + nt * 16 + l15, E - 1);
            gi[nt] = ei[row];
            gj[nt] = ei[E + row];
        }

        f32x4 acc[2][8];
        acc_bias_init(acc, b1, quad);

        half8 bef[2][4];

        // ---- layer 1, half 1: K = 0..127 (x_i features) ----
        #pragma unroll
        for (int nt = 0; nt < 2; ++nt) {
            const _Float16* pi = xh + (size_t)gi[nt] * HDIM;
            #pragma unroll
            for (int ks = 0; ks < 4; ++ks)
                bef[nt][ks] = *(const half8*)(pi + ks * 32 + quad * 8);
        }
        #pragma unroll
        for (int ks = 0; ks < 4; ++ks) {
            half8 aw[8];
            #pragma unroll
            for (int ct = 0; ct < 8; ++ct)
                aw[ct] = *(const half8*)(W1l + ((size_t)((ct * 8 + ks) * 64 + lane)) * 8);
            #pragma unroll
            for (int nt = 0; nt < 2; ++nt)
                #pragma unroll
                for (int ct = 0; ct < 8; ++ct)
                    acc[nt][ct] = __builtin_amdgcn_mfma_f32_16x16x32_f16(
                        aw[ct], bef[nt][ks], acc[nt][ct], 0, 0, 0);
        }

        // ---- layer 1, half 2: K = 128..255 (x_j features) ----
        #pragma unroll
        for (int nt = 0; nt < 2; ++nt) {
            const _Float16* pj = xh + (size_t)gj[nt] * HDIM;
            #pragma unroll
            for (int ks = 0; ks < 4; ++ks)
                bef[nt][ks] = *(const half8*)(pj + ks * 32 + quad * 8);
        }
        #pragma unroll
        for (int ks = 0; ks < 4; ++ks) {
            half8 aw[8];
            #pragma unroll
            for (int ct = 0; ct < 8; ++ct)
                aw[ct] = *(const half8*)(W1l + ((size_t)((ct * 8 + 4 + ks) * 64 + lane)) * 8);
            #pragma unroll
            for (int nt = 0; nt < 2; ++nt)
                #pragma unroll
                for (int ct = 0; ct < 8; ++ct)
                    acc[nt][ct] = __builtin_amdgcn_mfma_f32_16x16x32_f16(
                        aw[ct], bef[nt][ks], acc[nt][ct], 0, 0, 0);
        }

        half8 bh[2][4];
        epi_extract(acc, scr, l15, quad, sw, bh, b2);  // h1 -> B-frags, acc=b2
        layer_mfma(acc, W2l, bh, lane);                // layer 2
        epi_extract(acc, scr, l15, quad, sw, bh, b3);  // h2 -> B-frags, acc=b3
        layer_mfma(acc, W3l, bh, lane);                // layer 3 (acc has b3)

        // ---- layer 4: per-edge dot over hidden + sigmoid ----
        #pragma unroll
        for (int nt = 0; nt < 2; ++nt) {
            float s = 0.f;
            #pragma unroll
            for (int ct = 0; ct < 8; ++ct) {
                float4 w4v = *(const float4*)(W4 + ct * 16 + quad * 4);
                s += fmaxf(acc[nt][ct][0], 0.f) * w4v.x;
                s += fmaxf(acc[nt][ct][1], 0.f) * w4v.y;
                s += fmaxf(acc[nt][ct][2], 0.f) * w4v.z;
                s += fmaxf(acc[nt][ct][3], 0.f) * w4v.w;
            }
            s += __shfl_xor(s, 16, 64);   // sum across quads (same l15)
            s += __shfl_xor(s, 32, 64);
            const int row = base + nt * 16 + l15;
            if (quad == 0 && row < E)
                out[row] = 1.f / (1.f + __expf(-(s + b4v)));
        }
    }
}

// ---------------------------------------------------------------------------
extern "C" void kernel_launch(void* const* d_in, const int* in_sizes, int n_in,
                              void* d_out, int out_size, void* d_ws, size_t ws_size,
                              hipStream_t stream)
{
    const float* x  = (const float*)d_in[0];
    const int*   ei = (const int*)d_in[1];
    const float* W1 = (const float*)d_in[2];
    const float* b1 = (const float*)d_in[3];
    const float* W2 = (const float*)d_in[4];
    const float* b2 = (const float*)d_in[5];
    const float* W3 = (const float*)d_in[6];
    const float* b3 = (const float*)d_in[7];
    const float* W4 = (const float*)d_in[8];
    const float* b4 = (const float*)d_in[9];
    float* out = (float*)d_out;

    const int NF = in_sizes[0];    // N*F = 12,800,000
    const int E  = out_size;       // 625,000

    // ws layout (halfs): [ xh : NF ][ W1p : 32768 ][ W2p : 16384 ][ W3p : 16384 ]
    _Float16* xh  = (_Float16*)d_ws;
    _Float16* W1p = xh + NF;
    _Float16* W2p = W1p + 32768;
    _Float16* W3p = W2p + 16384;

    const int xblocks = (NF + 2047) / 2048;
    prep_kernel<<<32 + xblocks, 256, 0, stream>>>(x, W1, W2, W3, xh, W1p, W2p, W3p, NF);

    hipFuncSetAttribute((const void*)edge_mlp_kernel,
                        hipFuncAttributeMaxDynamicSharedMemorySize, LDS_BYTES);
    edge_mlp_kernel<<<256, 512, LDS_BYTES, stream>>>(ei, xh, W1p,
                                                     b1, b2, b3, W4, b4, out, E);
}

// Round 5
// 192.079 us; speedup vs baseline: 1.3325x; 1.1033x over previous
//
#include <hip/hip_runtime.h>
#include <math.h>

typedef _Float16 half8 __attribute__((ext_vector_type(8)));
typedef _Float16 half4 __attribute__((ext_vector_type(4)));
typedef float f32x4 __attribute__((ext_vector_type(4)));

#define HDIM 128
#define WHALFS 65536                      // packed W1|W2|W3 total halfs (128 KB)
#define SCR_HALFS 2048                    // per-wave scratch: 16 rows x 128 halfs (4 KB), XOR-swizzled
#define LDS_HALFS (WHALFS + 8 * SCR_HALFS)  // 81920 halfs
#define LDS_BYTES (LDS_HALFS * 2)           // 163840 B == 160 KiB exactly

// ---------------------------------------------------------------------------
// Prep: x (N x 128 fp32) -> fp16; pack W1/W2/W3 into MFMA *A-operand* frag
// order for the transposed GEMM (A = W^T):
//   frag(ct,ks), lane: A[m=ct*16+(lane&15)][k=ks*32+(lane>>4)*8+j] = W[k][m]
// ---------------------------------------------------------------------------
__global__ __launch_bounds__(256) void prep_kernel(
    const float* __restrict__ x,  const float* __restrict__ W1,
    const float* __restrict__ W2, const float* __restrict__ W3,
    _Float16* __restrict__ xh,  _Float16* __restrict__ W1p,
    _Float16* __restrict__ W2p, _Float16* __restrict__ W3p, int NF)
{
    int bid = blockIdx.x;
    if (bid < 32) {
        int t = bid * 256 + threadIdx.x;   // 0..8191
        const float* W; _Float16* Wp; int KS; int u;
        if (t < 4096)      { W = W1; Wp = W1p; KS = 8; u = t; }          // 256x128
        else if (t < 6144) { W = W2; Wp = W2p; KS = 4; u = t - 4096; }   // 128x128
        else               { W = W3; Wp = W3p; KS = 4; u = t - 6144; }   // 128x128
        int lane = u & 63;
        int fk   = u >> 6;            // ct*KS + ks
        int ks   = fk % KS;
        int ct   = fk / KS;
        int m    = ct * 16 + (lane & 15);
        int k0   = ks * 32 + (lane >> 4) * 8;
        half8 v;
        #pragma unroll
        for (int j = 0; j < 8; ++j) v[j] = (_Float16)W[(k0 + j) * HDIM + m];
        *(half8*)(Wp + (size_t)u * 8) = v;
    } else {
        long i = (long)(bid - 32) * 2048 + (long)threadIdx.x * 8;
        if (i + 8 <= (long)NF) {
            const float4* xf = (const float4*)(x + i);
            float4 f0 = xf[0], f1 = xf[1];
            half8 v;
            v[0] = (_Float16)f0.x; v[1] = (_Float16)f0.y;
            v[2] = (_Float16)f0.z; v[3] = (_Float16)f0.w;
            v[4] = (_Float16)f1.x; v[5] = (_Float16)f1.y;
            v[6] = (_Float16)f1.z; v[7] = (_Float16)f1.w;
            *(half8*)(xh + i) = v;
        }
    }
}

// ---------------------------------------------------------------------------
// acc init = per-layer bias (exact: acc elem j <-> out-channel ct*16+quad*4+j,
// bias is constant over columns).  Per-ct streaming keeps the live set small.
// ---------------------------------------------------------------------------
__device__ __forceinline__ void acc_bias_init(
    f32x4 (&acc)[2][8], const float* __restrict__ bias, int quad)
{
    #pragma unroll
    for (int ct = 0; ct < 8; ++ct) {
        float4 bv = *(const float4*)(bias + ct * 16 + quad * 4);
        f32x4 b = {bv.x, bv.y, bv.z, bv.w};
        acc[0][ct] = b;
        acc[1][ct] = b;
    }
}

// ---------------------------------------------------------------------------
// Epilogue: relu(acc) -> fp16 scratch [edge(l15)][hidden] (bias already in
// acc), pull next layer's B-frags back as b128, then re-init acc with the
// NEXT layer's bias.  Scratch row stride 128 halfs (256 B), XOR swizzle
// idx ^= (l15&7)<<3: b64 writes at 2-way bank aliasing (free), b128 reads
// equivalent to contiguous; 4 KB/wave.
// ---------------------------------------------------------------------------
__device__ __forceinline__ void epi_extract(
    f32x4 (&acc)[2][8], _Float16* __restrict__ scr, int l15, int quad, int sw,
    half8 (&bh)[2][4], const float* __restrict__ next_bias)
{
    #pragma unroll
    for (int nt = 0; nt < 2; ++nt) {
        #pragma unroll
        for (int ct = 0; ct < 8; ++ct) {
            half4 h;
            h[0] = (_Float16)fmaxf(acc[nt][ct][0], 0.f);
            h[1] = (_Float16)fmaxf(acc[nt][ct][1], 0.f);
            h[2] = (_Float16)fmaxf(acc[nt][ct][2], 0.f);
            h[3] = (_Float16)fmaxf(acc[nt][ct][3], 0.f);
            *(half4*)(scr + ((l15 * 128 + ct * 16 + quad * 4) ^ sw)) = h; // ds_write_b64
        }
        #pragma unroll
        for (int ks = 0; ks < 4; ++ks)                                    // ds_read_b128
            bh[nt][ks] = *(const half8*)(scr + ((l15 * 128 + ks * 32 + quad * 8) ^ sw));
    }
    acc_bias_init(acc, next_bias, quad);
}

// ---------------------------------------------------------------------------
// MFMA layer with ct CHUNKED 8 -> 2x4: peak live aw = 16 regs (32 with
// scheduler lookahead) instead of 32-64.  This is the R5 spill fix: the
// unrolled 8-wide aw batches (plus next-ks pipelining) were the arch-reg
// overflow driving ~16 MB/dispatch of scratch spill at the forced 128-arch
// split (R1-R4 evidence: VGPR pinned 128, WRITE_SIZE 18-91 MB).
// ---------------------------------------------------------------------------
__device__ __forceinline__ void layer_mfma(
    f32x4 (&acc)[2][8], const _Float16* __restrict__ Wl,
    half8 (&bh)[2][4], int lane)
{
    #pragma unroll
    for (int ks = 0; ks < 4; ++ks) {
        #pragma unroll
        for (int ch = 0; ch < 2; ++ch) {
            half8 aw[4];
            #pragma unroll
            for (int c = 0; c < 4; ++c)
                aw[c] = *(const half8*)(Wl + ((size_t)(((ch * 4 + c) * 4 + ks) * 64 + lane)) * 8);
            #pragma unroll
            for (int nt = 0; nt < 2; ++nt)
                #pragma unroll
                for (int c = 0; c < 4; ++c)
                    acc[nt][ch * 4 + c] = __builtin_amdgcn_mfma_f32_16x16x32_f16(
                        aw[c], bh[nt][ks], acc[nt][ch * 4 + c], 0, 0, 0);
        }
    }
}

// ---------------------------------------------------------------------------
// Persistent fused MLP, transposed GEMM: D[hidden][edge] = W^T (A) x ef^T (B).
// grid = 256 blocks x 512 thr (8 waves, 2 waves/SIMD); 160 KiB LDS ->
// 1 block/CU.  Any 512-thr block caps regs at 256/wave (8 waves must
// co-reside); compiler splits 128 arch / 128 accum.  Arch peak is kept
// < 128 by: nt=2 (acc=64 accum), layer-1 half-split (bef[2][4]=32),
// bias-in-acc (no bias regs in epi), and 4-wide aw/w4 chunking everywhere.
// ---------------------------------------------------------------------------
__global__ __launch_bounds__(512, 2) void edge_mlp_kernel(
    const int* __restrict__ ei, const _Float16* __restrict__ xh,
    const _Float16* __restrict__ wpack,   // W1p|W2p|W3p contiguous, 65536 halfs
    const float* __restrict__ b1, const float* __restrict__ b2,
    const float* __restrict__ b3, const float* __restrict__ W4,
    const float* __restrict__ b4, float* __restrict__ out, int E)
{
    extern __shared__ _Float16 lds[];

    // stage 128 KB of packed weights, once per (persistent) block
    {
        float4* dst = (float4*)lds;
        const float4* src = (const float4*)wpack;
        #pragma unroll
        for (int i = 0; i < 16; ++i)
            dst[i * 512 + threadIdx.x] = src[i * 512 + threadIdx.x];
    }
    __syncthreads();

    const int tid  = threadIdx.x;
    const int wave = tid >> 6;
    const int lane = tid & 63;
    const int l15  = lane & 15;
    const int quad = lane >> 4;
    const int sw   = (l15 & 7) << 3;      // scratch XOR swizzle (halfs)

    const _Float16* W1l = lds;
    const _Float16* W2l = lds + 32768;
    const _Float16* W3l = lds + 49152;
    _Float16* scr = lds + WHALFS + wave * SCR_HALFS;

    const int ntiles = (E + 255) >> 8;    // 256 edges per block tile
    const float b4v = b4[0];

    for (int t = blockIdx.x; t < ntiles; t += gridDim.x) {
        const int base = t * 256 + wave * 32;

        // edge indices for both n-tiles
        int gi[2], gj[2];
        #pragma unroll
        for (int nt = 0; nt < 2; ++nt) {
            const int row = min(base + nt * 16 + l15, E - 1);
            gi[nt] = ei[row];
            gj[nt] = ei[E + row];
        }

        f32x4 acc[2][8];
        acc_bias_init(acc, b1, quad);

        half8 bef[2][4];

        // ---- layer 1, half 1: K = 0..127 (x_i features) ----
        #pragma unroll
        for (int nt = 0; nt < 2; ++nt) {
            const _Float16* pi = xh + (size_t)gi[nt] * HDIM;
            #pragma unroll
            for (int ks = 0; ks < 4; ++ks)
                bef[nt][ks] = *(const half8*)(pi + ks * 32 + quad * 8);
        }
        #pragma unroll
        for (int ks = 0; ks < 4; ++ks) {
            #pragma unroll
            for (int ch = 0; ch < 2; ++ch) {
                half8 aw[4];
                #pragma unroll
                for (int c = 0; c < 4; ++c)
                    aw[c] = *(const half8*)(W1l + ((size_t)(((ch * 4 + c) * 8 + ks) * 64 + lane)) * 8);
                #pragma unroll
                for (int nt = 0; nt < 2; ++nt)
                    #pragma unroll
                    for (int c = 0; c < 4; ++c)
                        acc[nt][ch * 4 + c] = __builtin_amdgcn_mfma_f32_16x16x32_f16(
                            aw[c], bef[nt][ks], acc[nt][ch * 4 + c], 0, 0, 0);
            }
        }

        // ---- layer 1, half 2: K = 128..255 (x_j features) ----
        #pragma unroll
        for (int nt = 0; nt < 2; ++nt) {
            const _Float16* pj = xh + (size_t)gj[nt] * HDIM;
            #pragma unroll
            for (int ks = 0; ks < 4; ++ks)
                bef[nt][ks] = *(const half8*)(pj + ks * 32 + quad * 8);
        }
        #pragma unroll
        for (int ks = 0; ks < 4; ++ks) {
            #pragma unroll
            for (int ch = 0; ch < 2; ++ch) {
                half8 aw[4];
                #pragma unroll
                for (int c = 0; c < 4; ++c)
                    aw[c] = *(const half8*)(W1l + ((size_t)(((ch * 4 + c) * 8 + 4 + ks) * 64 + lane)) * 8);
                #pragma unroll
                for (int nt = 0; nt < 2; ++nt)
                    #pragma unroll
                    for (int c = 0; c < 4; ++c)
                        acc[nt][ch * 4 + c] = __builtin_amdgcn_mfma_f32_16x16x32_f16(
                            aw[c], bef[nt][ks], acc[nt][ch * 4 + c], 0, 0, 0);
            }
        }

        half8 bh[2][4];
        epi_extract(acc, scr, l15, quad, sw, bh, b2);  // h1 -> B-frags, acc=b2
        layer_mfma(acc, W2l, bh, lane);                // layer 2
        epi_extract(acc, scr, l15, quad, sw, bh, b3);  // h2 -> B-frags, acc=b3
        layer_mfma(acc, W3l, bh, lane);                // layer 3 (acc has b3)

        // ---- layer 4: per-edge dot over hidden + sigmoid (per-ct streaming) ----
        #pragma unroll
        for (int nt = 0; nt < 2; ++nt) {
            float s = 0.f;
            #pragma unroll
            for (int ct = 0; ct < 8; ++ct) {
                float4 w4v = *(const float4*)(W4 + ct * 16 + quad * 4);
                s += fmaxf(acc[nt][ct][0], 0.f) * w4v.x;
                s += fmaxf(acc[nt][ct][1], 0.f) * w4v.y;
                s += fmaxf(acc[nt][ct][2], 0.f) * w4v.z;
                s += fmaxf(acc[nt][ct][3], 0.f) * w4v.w;
            }
            s += __shfl_xor(s, 16, 64);   // sum across quads (same l15)
            s += __shfl_xor(s, 32, 64);
            const int row = base + nt * 16 + l15;
            if (quad == 0 && row < E)
                out[row] = 1.f / (1.f + __expf(-(s + b4v)));
        }
    }
}

// ---------------------------------------------------------------------------
extern "C" void kernel_launch(void* const* d_in, const int* in_sizes, int n_in,
                              void* d_out, int out_size, void* d_ws, size_t ws_size,
                              hipStream_t stream)
{
    const float* x  = (const float*)d_in[0];
    const int*   ei = (const int*)d_in[1];
    const float* W1 = (const float*)d_in[2];
    const float* b1 = (const float*)d_in[3];
    const float* W2 = (const float*)d_in[4];
    const float* b2 = (const float*)d_in[5];
    const float* W3 = (const float*)d_in[6];
    const float* b3 = (const float*)d_in[7];
    const float* W4 = (const float*)d_in[8];
    const float* b4 = (const float*)d_in[9];
    float* out = (float*)d_out;

    const int NF = in_sizes[0];    // N*F = 12,800,000
    const int E  = out_size;       // 625,000

    // ws layout (halfs): [ xh : NF ][ W1p : 32768 ][ W2p : 16384 ][ W3p : 16384 ]
    _Float16* xh  = (_Float16*)d_ws;
    _Float16* W1p = xh + NF;
    _Float16* W2p = W1p + 32768;
    _Float16* W3p = W2p + 16384;

    const int xblocks = (NF + 2047) / 2048;
    prep_kernel<<<32 + xblocks, 256, 0, stream>>>(x, W1, W2, W3, xh, W1p, W2p, W3p, NF);

    hipFuncSetAttribute((const void*)edge_mlp_kernel,
                        hipFuncAttributeMaxDynamicSharedMemorySize, LDS_BYTES);
    edge_mlp_kernel<<<256, 512, LDS_BYTES, stream>>>(ei, xh, W1p,
                                                     b1, b2, b3, W4, b4, out, E);
}